// Round 18
// baseline (124.714 us; speedup 1.0000x reference)
//
#include <hip/hip_runtime.h>
#include <stdint.h>

#define Bb 2
#define Tt 2048
#define Dd 1024
#define Hh 16
#define HDd 64
#define Mm 4096   // Bb*Tt

typedef __attribute__((ext_vector_type(4))) float f32x4;
typedef __attribute__((ext_vector_type(16))) float f32x16;
typedef __attribute__((ext_vector_type(8))) __bf16 bf16x8;
typedef __attribute__((ext_vector_type(8))) short s16x8;
typedef __attribute__((ext_vector_type(4))) float fvec4;
typedef __attribute__((ext_vector_type(4))) unsigned int u32x4;

__device__ __forceinline__ float bf2f(ushort u){
  union { unsigned int i; float f; } v; v.i = ((unsigned int)u) << 16; return v.f;
}
__device__ __forceinline__ ushort f2bf(float f){
  union { float f; unsigned int i; } v; v.f = f;
  unsigned int u = v.i;
  u += 0x7FFFu + ((u >> 16) & 1u);   // round-to-nearest-even
  return (ushort)(u >> 16);
}

__device__ __forceinline__ void gload16(const void* g, void* l){
  __builtin_amdgcn_global_load_lds(
      (const __attribute__((address_space(1))) void*)g,
      (__attribute__((address_space(3))) void*)l, 16, 0, 0);
}

// ---------------- fused fp32 -> bf16 convert (all 6 tensors, one launch) ----------------
__global__ __launch_bounds__(256) void cvt_all(
    const float* __restrict__ q, const float* __restrict__ kv,
    const float* __restrict__ wq, const float* __restrict__ wk,
    const float* __restrict__ wv, const float* __restrict__ wo,
    ushort* __restrict__ oq, ushort* __restrict__ okv, ushort* __restrict__ owq,
    ushort* __restrict__ owk, ushort* __restrict__ owv, ushort* __restrict__ owo)
{
  const int NQ = Mm*Dd/4;     // 1048576 vec4
  const int NW = Dd*Dd/4;     // 262144 vec4
  int j = blockIdx.x * 256 + threadIdx.x;   // grid covers 2*NQ+4*NW exactly
  const float* s; ushort* d;
  if (j < NQ)            { s = q;  d = oq;  }
  else if ((j -= NQ) < NQ){ s = kv; d = okv; }
  else if ((j -= NQ) < NW){ s = wq; d = owq; }
  else if ((j -= NW) < NW){ s = wk; d = owk; }
  else if ((j -= NW) < NW){ s = wv; d = owv; }
  else        { j -= NW;   s = wo; d = owo; }
  fvec4 v = ((const fvec4*)s)[j];
  unsigned int lo = (unsigned int)f2bf(v.x) | ((unsigned int)f2bf(v.y) << 16);
  unsigned int hi = (unsigned int)f2bf(v.z) | ((unsigned int)f2bf(v.w) << 16);
  ((uint2*)d)[j] = make_uint2(lo, hi);
}

// ---------------- projection body: 128x64 tile, 4 waves x (32 rows x 64 cols) ----------------
// MODE 1: bf16 out + per-64-col RMSNorm (*rmsScale).  MODE 0: bf16 out plain.
template<int MODE>
__device__ __forceinline__ void proj_body(char* smem,
    const ushort* __restrict__ A, const ushort* __restrict__ W,
    const float* __restrict__ bias, const float* __restrict__ nw, float rmsScale,
    ushort* __restrict__ Oh, int m0, int n0)
{
  ushort* As = (ushort*)smem;
  ushort* Bs = (ushort*)(smem + 16384);
  const int tid  = threadIdx.x;
  const int w    = tid >> 6, lid = tid & 63;
  const int lrow = lid & 15, g = lid >> 4;
  const int wm   = w << 5;                 // wave rows: w*32

  f32x4 acc[2][4] = {};

  for (int kt = 0; kt < Dd; kt += 64){
    __syncthreads();
    #pragma unroll
    for (int i = 0; i < 4; ++i){
      int e   = tid + i*256;
      int row = e >> 3;
      int c   = (e & 7) ^ (row & 7);   // pre-swizzle global source (linear LDS dest)
      gload16(A + (size_t)(m0 + row)*Dd + kt + c*8, &As[e*8]);
    }
    #pragma unroll
    for (int i = 0; i < 2; ++i){
      int e   = tid + i*256;
      int row = e >> 3;
      int c   = (e & 7) ^ (row & 7);
      gload16(W + (size_t)(n0 + row)*Dd + kt + c*8, &Bs[e*8]);
    }
    __syncthreads();
    #pragma unroll
    for (int kc = 0; kc < 2; ++kc){
      bf16x8 af[2], bfr[4];
      #pragma unroll
      for (int r = 0; r < 2; ++r){
        int row = wm + r*16 + lrow;
        af[r] = *(const bf16x8*)&As[row*64 + (((kc*4 + g) ^ (row & 7)) << 3)];
      }
      #pragma unroll
      for (int c = 0; c < 4; ++c){
        int row = c*16 + lrow;
        bfr[c] = *(const bf16x8*)&Bs[row*64 + (((kc*4 + g) ^ (row & 7)) << 3)];
      }
      #pragma unroll
      for (int r = 0; r < 2; ++r)
        #pragma unroll
        for (int c = 0; c < 4; ++c)
          acc[r][c] = __builtin_amdgcn_mfma_f32_16x16x32_bf16(af[r], bfr[c], acc[r][c], 0, 0, 0);
    }
  }
  // epilogue: D row=(lane>>4)*4+b, col=lane&15
  float bv[4], wv4[4];
  #pragma unroll
  for (int c = 0; c < 4; ++c){
    bv[c] = bias[n0 + c*16 + lrow];
    if (MODE == 1) wv4[c] = nw[c*16 + lrow];   // head dim = col % 64 = c*16+lrow
  }
  #pragma unroll
  for (int r = 0; r < 2; ++r){
    #pragma unroll
    for (int b = 0; b < 4; ++b){
      float v[4];
      #pragma unroll
      for (int c = 0; c < 4; ++c) v[c] = acc[r][c][b] + bv[c];
      float sc = 1.0f;
      if (MODE == 1){
        // wave's 64 cols (c,lrow) = exactly one 64-dim head group
        float ss = v[0]*v[0] + v[1]*v[1] + v[2]*v[2] + v[3]*v[3];
        ss += __shfl_xor(ss, 1, 64);
        ss += __shfl_xor(ss, 2, 64);
        ss += __shfl_xor(ss, 4, 64);
        ss += __shfl_xor(ss, 8, 64);
        sc = rsqrtf(ss * (1.0f/64.0f) + 1e-6f) * rmsScale;
      }
      int row = m0 + wm + r*16 + g*4 + b;
      #pragma unroll
      for (int c = 0; c < 4; ++c){
        int col = n0 + c*16 + lrow;
        if (MODE == 1) Oh[(size_t)row*Dd + col] = f2bf(v[c] * sc * wv4[c]);
        else           Oh[(size_t)row*Dd + col] = f2bf(v[c]);
      }
    }
  }
}

// ---------------- QKV projections: 1536 blocks of 128x64 tiles (6 blocks/CU) -----------
__global__ __launch_bounds__(256) void gemm_qkv(
  const ushort* __restrict__ qbf, const ushort* __restrict__ kvbf,
  const ushort* __restrict__ wq, const ushort* __restrict__ wk, const ushort* __restrict__ wv,
  const float* __restrict__ bq, const float* __restrict__ bk, const float* __restrict__ bv,
  const float* __restrict__ qnw, const float* __restrict__ knw,
  ushort* __restrict__ Q, ushort* __restrict__ Kx, ushort* __restrict__ V)
{
  __shared__ char smem[24576];
  // XCD-aware bijective swizzle (1536 = 8 * 192); consecutive ids share the A-panel (mt)
  int bid  = (blockIdx.x & 7) * 192 + (blockIdx.x >> 3);
  int proj = bid >> 9;          // /512
  int rem  = bid & 511;
  int mt   = rem >> 4, nt = rem & 15;
  // Q gets rmsnorm * (0.125 * log2e)  -> softmax scale folded in; exp2 used directly
  if (proj == 0)
    proj_body<1>(smem, qbf, wq, bq, qnw, 0.18033688011112042f, Q, mt*128, nt*64);
  else if (proj == 1)
    proj_body<1>(smem, kvbf, wk, bk, knw, 1.0f, Kx, mt*128, nt*64);
  else
    proj_body<0>(smem, kvbf, wv, bv, nullptr, 1.0f, V, mt*128, nt*64);
}

// ---------------- O projection: 128x64 tile, 512 blocks (2 blocks/CU) ----------------
__global__ __launch_bounds__(256) void gemm_o(
  const ushort* __restrict__ X, const ushort* __restrict__ wo,
  const float* __restrict__ bo, float* __restrict__ out)
{
  __shared__ char smem[24576];
  ushort* As = (ushort*)smem;
  ushort* Bs = (ushort*)(smem + 16384);
  int bid = (blockIdx.x & 7) * 64 + (blockIdx.x >> 3);   // XCD swizzle (512 = 8 * 64)
  const int mt = bid >> 4, nt = bid & 15;
  const int m0 = mt*128, n0 = nt*64;

  const int tid  = threadIdx.x;
  const int w    = tid >> 6, lid = tid & 63;
  const int lrow = lid & 15, g = lid >> 4;
  const int wm   = (w >> 1) << 6, wn = (w & 1) << 5;   // wave: 64 rows x 32 cols

  f32x4 acc[4][2] = {};

  for (int kt = 0; kt < Dd; kt += 64){
    __syncthreads();
    #pragma unroll
    for (int i = 0; i < 4; ++i){
      int e   = tid + i*256;
      int row = e >> 3;
      int c   = (e & 7) ^ (row & 7);
      gload16(X + (size_t)(m0 + row)*Dd + kt + c*8, &As[e*8]);
    }
    #pragma unroll
    for (int i = 0; i < 2; ++i){
      int e   = tid + i*256;
      int row = e >> 3;
      int c   = (e & 7) ^ (row & 7);
      gload16(wo + (size_t)(n0 + row)*Dd + kt + c*8, &Bs[e*8]);
    }
    __syncthreads();
    #pragma unroll
    for (int kc = 0; kc < 2; ++kc){
      bf16x8 af[4], bfr[2];
      #pragma unroll
      for (int r = 0; r < 4; ++r){
        int row = wm + r*16 + lrow;
        af[r] = *(const bf16x8*)&As[row*64 + (((kc*4 + g) ^ (row & 7)) << 3)];
      }
      #pragma unroll
      for (int c = 0; c < 2; ++c){
        int row = wn + c*16 + lrow;
        bfr[c] = *(const bf16x8*)&Bs[row*64 + (((kc*4 + g) ^ (row & 7)) << 3)];
      }
      #pragma unroll
      for (int r = 0; r < 4; ++r)
        #pragma unroll
        for (int c = 0; c < 2; ++c)
          acc[r][c] = __builtin_amdgcn_mfma_f32_16x16x32_bf16(af[r], bfr[c], acc[r][c], 0, 0, 0);
    }
  }
  const int colbase = n0 + wn;
  float bv[2];
  #pragma unroll
  for (int c = 0; c < 2; ++c) bv[c] = bo[colbase + c*16 + lrow];
  #pragma unroll
  for (int r = 0; r < 4; ++r){
    #pragma unroll
    for (int b = 0; b < 4; ++b){
      int row = m0 + wm + r*16 + g*4 + b;
      #pragma unroll
      for (int c = 0; c < 2; ++c){
        int col = colbase + c*16 + lrow;
        out[(size_t)row*Dd + col] = acc[r][c][b] + bv[c];
      }
    }
  }
}

// ---------------- flash attention: 64q blocks, 3 blocks/CU, static-max softmax --------
// grid = 32 qt * 32 bh (XCD-swizzled), 1024 blocks; block = 4 waves = {2 q-waves of
// 32q} x {2 kv-halves}. LDS 48KB: per half K dbuf 2x8KB + V SINGLE 8KB -> 3 blocks/CU
// (12 waves/CU, was grid-capped at 8). V single-buffer needs a 2nd barrier per tile
// (PV-done before next scatter); K dbuf DMA still spans the whole tile body.
// All fragment layouts / swizzles / dosm identical to the round-13-verified kernel.
__global__ __launch_bounds__(256, 3) void attn_k(
  const ushort* __restrict__ Qb, const ushort* __restrict__ Kb,
  const ushort* __restrict__ Vb, ushort* __restrict__ Ob)
{
  __shared__ char L[49152];   // half h at h*24576: K dbuf 2x8KB at +0, V single 8KB at +16384

  const int tid  = threadIdx.x;
  const int w    = tid >> 6, lid = tid & 63;
  const int half = w >> 1,  qw = w & 1;
  const int c31  = lid & 31, hi = lid >> 5;
  const int ti   = tid & 127;          // index within half (2 waves): ti = qw*64 + lid

  int bid = blockIdx.x;
  int wg  = (bid & 7) * 128 + (bid >> 3);   // 1024 blocks -> 8 XCD contiguous chunks
  int bh  = wg >> 5, qt = wg & 31;          // 32 qt tiles of 64 q
  int bb  = bh >> 4, hh = bh & 15;
  const size_t base = (size_t)bb * Tt * Dd + (size_t)hh * HDd;

  // Q fragments (B-operand): lane holds Q[q = qt*64 + qw*32 + c31][kc*16 + hi*8 ..]
  bf16x8 qf[4];
  #pragma unroll
  for (int kc = 0; kc < 4; ++kc)
    qf[kc] = *(const bf16x8*)&Qb[base + (size_t)(qt*64 + qw*32 + c31)*Dd + kc*16 + hi*8];

  char* Kl = L + half*24576;           // K dbuf (2 x 8KB)
  char* Vl = Kl + 16384;               // V single (8KB)

  // hoisted K-frag offsets [kh][kc]: row = kh*32+c31, chunk (2kc+hi)^(row&7)
  int kfo[2][4];
  #pragma unroll
  for (int kh = 0; kh < 2; ++kh)
    #pragma unroll
    for (int kc = 0; kc < 4; ++kc)
      kfo[kh][kc] = (kh*32 + c31)*128 + (((2*kc + hi) ^ (c31 & 7)) << 4);

  // hoisted V^T-frag offsets [dh][kc']: row = d = dh*32+c31, chunk (2kc'+hi)^F(d)
  int vfo[2][4];
  #pragma unroll
  for (int dh = 0; dh < 2; ++dh){
    int d = dh*32 + c31, F = ((d >> 3) ^ d) & 7;
    #pragma unroll
    for (int kcp = 0; kcp < 4; ++kcp)
      vfo[dh][kcp] = d*128 + (((2*kcp + hi) ^ F) << 4);
  }

  // V^T scatter offsets: thread owns keys key0..+3, d d0..+7
  const int d0 = (ti & 7) * 8, key0 = (ti >> 3) * 4;
  int vso[8];
  {
    int m  = key0 >> 2;
    int c  = ((m >> 2) << 1) | (m & 1);
    int hb = ((m >> 1) & 1) * 8;
    #pragma unroll
    for (int dd = 0; dd < 8; ++dd){
      int d = d0 + dd, F = ((d >> 3) ^ d) & 7;
      vso[dd] = d*128 + ((c ^ F) << 4) + hb;
    }
  }

  // staging sources (running) + K LDS dests
  const ushort* ksg[4]; char* kdst[4];
  #pragma unroll
  for (int i = 0; i < 4; ++i){
    int e = ti + i*128;
    int row = e >> 3, cc = (e & 7) ^ (row & 7);
    ksg[i]  = Kb + base + (size_t)(half*1024 + row) * Dd + cc*8;
    kdst[i] = Kl + e*16;
  }
  const ushort* vsg = Vb + base + (size_t)(half*1024 + key0) * Dd + d0;
  const size_t kstep = (size_t)64 * Dd;

  // prologue: K tile0 -> Kbuf0 (DMA), V tile0 -> regs
  #pragma unroll
  for (int i = 0; i < 4; ++i) gload16(ksg[i], kdst[i]);
  u32x4 vv0 = *(const u32x4*)(vsg);
  u32x4 vv1 = *(const u32x4*)(vsg + Dd);
  u32x4 vv2 = *(const u32x4*)(vsg + 2*Dd);
  u32x4 vv3 = *(const u32x4*)(vsg + 3*Dd);
  #pragma unroll
  for (int i = 0; i < 4; ++i) ksg[i] += kstep;
  vsg += kstep;

  f32x16 o[2] = {};            // o[dh]: O^T[d = dh*32+(reg&3)+8(reg>>2)+4hi][q = c31]
  f32x16 lacc = {};            // row-sum accumulator (all regs equal per lane)
  const __bf16 one1 = (__bf16)1.0f;
  const bf16x8 ones = {one1, one1, one1, one1, one1, one1, one1, one1};

  // V^T scatter into single buffer: 16 v_perm + 8 ds_write_b64
  auto vscatter = [&](){
    #pragma unroll
    for (int dd = 0; dd < 8; ++dd){
      unsigned sel = (dd & 1) ? 0x07060302u : 0x05040100u;
      unsigned lo  = __builtin_amdgcn_perm(vv1[dd >> 1], vv0[dd >> 1], sel);
      unsigned hi2 = __builtin_amdgcn_perm(vv3[dd >> 1], vv2[dd >> 1], sel);
      *(uint2*)(Vl + vso[dd]) = make_uint2(lo, hi2);
    }
  };

  // static-max softmax: P = exp2(s) in place (|s|<=11.54 guaranteed), then pack.
  auto dosm = [&](f32x16* s, bf16x8* pao){
    #pragma unroll
    for (int kh = 0; kh < 2; ++kh)
      #pragma unroll
      for (int i = 0; i < 16; ++i)
        s[kh][i] = __builtin_amdgcn_exp2f(s[kh][i]);
    #pragma unroll
    for (int kh = 0; kh < 2; ++kh)
      #pragma unroll
      for (int c = 0; c < 2; ++c){
        unsigned u0, u1, u2, u3;
        asm("v_cvt_pk_bf16_f32 %0, %1, %2" : "=v"(u0) : "v"(s[kh][8*c+0]), "v"(s[kh][8*c+1]));
        asm("v_cvt_pk_bf16_f32 %0, %1, %2" : "=v"(u1) : "v"(s[kh][8*c+2]), "v"(s[kh][8*c+3]));
        asm("v_cvt_pk_bf16_f32 %0, %1, %2" : "=v"(u2) : "v"(s[kh][8*c+4]), "v"(s[kh][8*c+5]));
        asm("v_cvt_pk_bf16_f32 %0, %1, %2" : "=v"(u3) : "v"(s[kh][8*c+6]), "v"(s[kh][8*c+7]));
        u32x4 uu = {u0, u1, u2, u3};
        pao[kh*2 + c] = __builtin_bit_cast(bf16x8, uu);
      }
  };

#define ATTN_TILE(BUF, PREFETCH)                                                     \
  {                                                                                  \
    vscatter();                        /* V(t) -> single buffer (regs from t-1) */   \
    __syncthreads();                   /* A: scatter visible; K-DMA(t) drained  */   \
    if (PREFETCH){                                                                   \
      _Pragma("unroll")                                                              \
      for (int i = 0; i < 4; ++i){                                                   \
        gload16(ksg[i], kdst[i] + ((BUF)^1)*8192);                                   \
        ksg[i] += kstep;                                                             \
      }                                                                              \
      vv0 = *(const u32x4*)(vsg);                                                    \
      vv1 = *(const u32x4*)(vsg + Dd);                                               \
      vv2 = *(const u32x4*)(vsg + 2*Dd);                                             \
      vv3 = *(const u32x4*)(vsg + 3*Dd);                                             \
      vsg += kstep;                                                                  \
    }                                                                                \
    f32x16 s0[2] = {};                                                               \
    __builtin_amdgcn_s_setprio(1);                                                   \
    _Pragma("unroll")                                                                \
    for (int kh = 0; kh < 2; ++kh)                                                   \
      _Pragma("unroll")                                                              \
      for (int kc = 0; kc < 4; ++kc){                                                \
        bf16x8 kf = *(const bf16x8*)(Kl + kfo[kh][kc] + (BUF)*8192);                 \
        s0[kh] = __builtin_amdgcn_mfma_f32_32x32x16_bf16(kf, qf[kc], s0[kh], 0,0,0); \
      }                                                                              \
    __builtin_amdgcn_s_setprio(0);                                                   \
    bf16x8 pa0[4];                                                                   \
    dosm(s0, pa0);                                                                   \
    __builtin_amdgcn_s_setprio(1);                                                   \
    _Pragma("unroll")                                                                \
    for (int dh = 0; dh < 2; ++dh)                                                   \
      _Pragma("unroll")                                                              \
      for (int kcp = 0; kcp < 4; ++kcp){                                             \
        bf16x8 vf = *(const bf16x8*)(Vl + vfo[dh][kcp]);                             \
        o[dh] = __builtin_amdgcn_mfma_f32_32x32x16_bf16(vf, pa0[kcp], o[dh], 0,0,0); \
      }                                                                              \
    _Pragma("unroll")                                                                \
    for (int kcp = 0; kcp < 4; ++kcp)                                                \
      lacc = __builtin_amdgcn_mfma_f32_32x32x16_bf16(ones, pa0[kcp], lacc, 0,0,0);   \
    __builtin_amdgcn_s_setprio(0);                                                   \
    __syncthreads();                   /* B: PV reads of Vl done -> next scatter */  \
  }

  for (int kt2 = 0; kt2 < 8; ++kt2){
    ATTN_TILE(0, true);
    ATTN_TILE(1, (kt2 != 7));
  }
#undef ATTN_TILE

  // ---- merge halves through LDS: pub[i][ti] f32x4, i=0..8 (9*128*16B = 18KB)
  if (half == 1){
    #pragma unroll
    for (int dh = 0; dh < 2; ++dh)
      #pragma unroll
      for (int G = 0; G < 4; ++G){
        f32x4 v = { o[dh][4*G+0], o[dh][4*G+1], o[dh][4*G+2], o[dh][4*G+3] };
        *(f32x4*)(L + (((dh*4 + G)*128) + ti)*16) = v;
      }
    f32x4 ml = {lacc[0], 0.f, 0.f, 0.f};
    *(f32x4*)(L + ((8*128) + ti)*16) = ml;
  }
  __syncthreads();
  if (half == 0){
    f32x4 ml = *(const f32x4*)(L + ((8*128) + ti)*16);
    float inv = 1.0f / (lacc[0] + ml[0]);
    int qrow = qt*64 + qw*32 + c31;
    #pragma unroll
    for (int dh = 0; dh < 2; ++dh)
      #pragma unroll
      for (int G = 0; G < 4; ++G){
        f32x4 op = *(const f32x4*)(L + (((dh*4 + G)*128) + ti)*16);
        float oc0 = (o[dh][4*G+0] + op[0]) * inv;
        float oc1 = (o[dh][4*G+1] + op[1]) * inv;
        float oc2 = (o[dh][4*G+2] + op[2]) * inv;
        float oc3 = (o[dh][4*G+3] + op[3]) * inv;
        uint2 u;
        u.x = (unsigned)f2bf(oc0) | ((unsigned)f2bf(oc1) << 16);
        u.y = (unsigned)f2bf(oc2) | ((unsigned)f2bf(oc3) << 16);
        *(uint2*)&Ob[base + (size_t)qrow*Dd + dh*32 + 8*G + hi*4] = u;
      }
  }
}

extern "C" void kernel_launch(void* const* d_in, const int* in_sizes, int n_in,
                              void* d_out, int out_size, void* d_ws, size_t ws_size,
                              hipStream_t stream)
{
  const float* query = (const float*)d_in[0];
  const float* keyv  = (const float*)d_in[1];
  const float* Wq    = (const float*)d_in[2];
  const float* bq    = (const float*)d_in[3];
  const float* Wk    = (const float*)d_in[4];
  const float* bk    = (const float*)d_in[5];
  const float* Wv    = (const float*)d_in[6];
  const float* bv    = (const float*)d_in[7];
  const float* Wo    = (const float*)d_in[8];
  const float* bo    = (const float*)d_in[9];
  const float* qnw   = (const float*)d_in[10];
  const float* knw   = (const float*)d_in[11];
  float* out = (float*)d_out;

  char* p = (char*)d_ws;
  ushort* qbf  = (ushort*)p; p += (size_t)Mm*Dd*2;
  ushort* kvbf = (ushort*)p; p += (size_t)Mm*Dd*2;
  ushort* wqb  = (ushort*)p; p += (size_t)Dd*Dd*2;
  ushort* wkb  = (ushort*)p; p += (size_t)Dd*Dd*2;
  ushort* wvb  = (ushort*)p; p += (size_t)Dd*Dd*2;
  ushort* wob  = (ushort*)p; p += (size_t)Dd*Dd*2;
  ushort* Qb   = (ushort*)p; p += (size_t)Mm*Dd*2;
  ushort* Kbf  = (ushort*)p; p += (size_t)Mm*Dd*2;
  ushort* Vbf  = (ushort*)p; p += (size_t)Mm*Dd*2;
  ushort* Ab   = (ushort*)p; p += (size_t)Mm*Dd*2;

  cvt_all<<<dim3(12288), dim3(256), 0, stream>>>(query, keyv, Wq, Wk, Wv, Wo,
                                                 qbf, kvbf, wqb, wkb, wvb, wob);

  gemm_qkv<<<dim3(1536), dim3(256), 0, stream>>>(qbf, kvbf, wqb, wkb, wvb,
                                                 bq, bk, bv, qnw, knw, Qb, Kbf, Vbf);

  attn_k<<<dim3(1024), dim3(256), 0, stream>>>(Qb, Kbf, Vbf, Ab);

  gemm_o<<<dim3(512), dim3(256), 0, stream>>>(Ab, wob, bo, out);
}

// Round 19
// 116.411 us; speedup vs baseline: 1.0713x; 1.0713x over previous
//
#include <hip/hip_runtime.h>
#include <stdint.h>

#define Bb 2
#define Tt 2048
#define Dd 1024
#define Hh 16
#define HDd 64
#define Mm 4096   // Bb*Tt

typedef __attribute__((ext_vector_type(4))) float f32x4;
typedef __attribute__((ext_vector_type(16))) float f32x16;
typedef __attribute__((ext_vector_type(8))) __bf16 bf16x8;
typedef __attribute__((ext_vector_type(8))) short s16x8;
typedef __attribute__((ext_vector_type(4))) float fvec4;
typedef __attribute__((ext_vector_type(4))) unsigned int u32x4;

__device__ __forceinline__ float bf2f(ushort u){
  union { unsigned int i; float f; } v; v.i = ((unsigned int)u) << 16; return v.f;
}
__device__ __forceinline__ ushort f2bf(float f){
  union { float f; unsigned int i; } v; v.f = f;
  unsigned int u = v.i;
  u += 0x7FFFu + ((u >> 16) & 1u);   // round-to-nearest-even
  return (ushort)(u >> 16);
}

__device__ __forceinline__ void gload16(const void* g, void* l){
  __builtin_amdgcn_global_load_lds(
      (const __attribute__((address_space(1))) void*)g,
      (__attribute__((address_space(3))) void*)l, 16, 0, 0);
}

// ---------------- fused fp32 -> bf16 convert (all 6 tensors, one launch) ----------------
__global__ __launch_bounds__(256) void cvt_all(
    const float* __restrict__ q, const float* __restrict__ kv,
    const float* __restrict__ wq, const float* __restrict__ wk,
    const float* __restrict__ wv, const float* __restrict__ wo,
    ushort* __restrict__ oq, ushort* __restrict__ okv, ushort* __restrict__ owq,
    ushort* __restrict__ owk, ushort* __restrict__ owv, ushort* __restrict__ owo)
{
  const int NQ = Mm*Dd/4;     // 1048576 vec4
  const int NW = Dd*Dd/4;     // 262144 vec4
  int j = blockIdx.x * 256 + threadIdx.x;   // grid covers 2*NQ+4*NW exactly
  const float* s; ushort* d;
  if (j < NQ)            { s = q;  d = oq;  }
  else if ((j -= NQ) < NQ){ s = kv; d = okv; }
  else if ((j -= NQ) < NW){ s = wq; d = owq; }
  else if ((j -= NW) < NW){ s = wk; d = owk; }
  else if ((j -= NW) < NW){ s = wv; d = owv; }
  else        { j -= NW;   s = wo; d = owo; }
  fvec4 v = ((const fvec4*)s)[j];
  unsigned int lo = (unsigned int)f2bf(v.x) | ((unsigned int)f2bf(v.y) << 16);
  unsigned int hi = (unsigned int)f2bf(v.z) | ((unsigned int)f2bf(v.w) << 16);
  ((uint2*)d)[j] = make_uint2(lo, hi);
}

// ---------------- projection body: 128x64 tile, 4 waves x (32 rows x 64 cols) ----------------
// MODE 1: bf16 out + per-64-col RMSNorm (*rmsScale).  MODE 0: bf16 out plain.
template<int MODE>
__device__ __forceinline__ void proj_body(char* smem,
    const ushort* __restrict__ A, const ushort* __restrict__ W,
    const float* __restrict__ bias, const float* __restrict__ nw, float rmsScale,
    ushort* __restrict__ Oh, int m0, int n0)
{
  ushort* As = (ushort*)smem;
  ushort* Bs = (ushort*)(smem + 16384);
  const int tid  = threadIdx.x;
  const int w    = tid >> 6, lid = tid & 63;
  const int lrow = lid & 15, g = lid >> 4;
  const int wm   = w << 5;                 // wave rows: w*32

  f32x4 acc[2][4] = {};

  for (int kt = 0; kt < Dd; kt += 64){
    __syncthreads();
    #pragma unroll
    for (int i = 0; i < 4; ++i){
      int e   = tid + i*256;
      int row = e >> 3;
      int c   = (e & 7) ^ (row & 7);   // pre-swizzle global source (linear LDS dest)
      gload16(A + (size_t)(m0 + row)*Dd + kt + c*8, &As[e*8]);
    }
    #pragma unroll
    for (int i = 0; i < 2; ++i){
      int e   = tid + i*256;
      int row = e >> 3;
      int c   = (e & 7) ^ (row & 7);
      gload16(W + (size_t)(n0 + row)*Dd + kt + c*8, &Bs[e*8]);
    }
    __syncthreads();
    #pragma unroll
    for (int kc = 0; kc < 2; ++kc){
      bf16x8 af[2], bfr[4];
      #pragma unroll
      for (int r = 0; r < 2; ++r){
        int row = wm + r*16 + lrow;
        af[r] = *(const bf16x8*)&As[row*64 + (((kc*4 + g) ^ (row & 7)) << 3)];
      }
      #pragma unroll
      for (int c = 0; c < 4; ++c){
        int row = c*16 + lrow;
        bfr[c] = *(const bf16x8*)&Bs[row*64 + (((kc*4 + g) ^ (row & 7)) << 3)];
      }
      #pragma unroll
      for (int r = 0; r < 2; ++r)
        #pragma unroll
        for (int c = 0; c < 4; ++c)
          acc[r][c] = __builtin_amdgcn_mfma_f32_16x16x32_bf16(af[r], bfr[c], acc[r][c], 0, 0, 0);
    }
  }
  // epilogue: D row=(lane>>4)*4+b, col=lane&15
  float bv[4], wv4[4];
  #pragma unroll
  for (int c = 0; c < 4; ++c){
    bv[c] = bias[n0 + c*16 + lrow];
    if (MODE == 1) wv4[c] = nw[c*16 + lrow];   // head dim = col % 64 = c*16+lrow
  }
  #pragma unroll
  for (int r = 0; r < 2; ++r){
    #pragma unroll
    for (int b = 0; b < 4; ++b){
      float v[4];
      #pragma unroll
      for (int c = 0; c < 4; ++c) v[c] = acc[r][c][b] + bv[c];
      float sc = 1.0f;
      if (MODE == 1){
        // wave's 64 cols (c,lrow) = exactly one 64-dim head group
        float ss = v[0]*v[0] + v[1]*v[1] + v[2]*v[2] + v[3]*v[3];
        ss += __shfl_xor(ss, 1, 64);
        ss += __shfl_xor(ss, 2, 64);
        ss += __shfl_xor(ss, 4, 64);
        ss += __shfl_xor(ss, 8, 64);
        sc = rsqrtf(ss * (1.0f/64.0f) + 1e-6f) * rmsScale;
      }
      int row = m0 + wm + r*16 + g*4 + b;
      #pragma unroll
      for (int c = 0; c < 4; ++c){
        int col = n0 + c*16 + lrow;
        if (MODE == 1) Oh[(size_t)row*Dd + col] = f2bf(v[c] * sc * wv4[c]);
        else           Oh[(size_t)row*Dd + col] = f2bf(v[c]);
      }
    }
  }
}

// ---------------- QKV projections: 1536 blocks of 128x64 tiles (6 blocks/CU) -----------
__global__ __launch_bounds__(256) void gemm_qkv(
  const ushort* __restrict__ qbf, const ushort* __restrict__ kvbf,
  const ushort* __restrict__ wq, const ushort* __restrict__ wk, const ushort* __restrict__ wv,
  const float* __restrict__ bq, const float* __restrict__ bk, const float* __restrict__ bv,
  const float* __restrict__ qnw, const float* __restrict__ knw,
  ushort* __restrict__ Q, ushort* __restrict__ Kx, ushort* __restrict__ V)
{
  __shared__ char smem[24576];
  // XCD-aware bijective swizzle (1536 = 8 * 192); consecutive ids share the A-panel (mt)
  int bid  = (blockIdx.x & 7) * 192 + (blockIdx.x >> 3);
  int proj = bid >> 9;          // /512
  int rem  = bid & 511;
  int mt   = rem >> 4, nt = rem & 15;
  // Q gets rmsnorm * (0.125 * log2e)  -> softmax scale folded in; exp2 used directly
  if (proj == 0)
    proj_body<1>(smem, qbf, wq, bq, qnw, 0.18033688011112042f, Q, mt*128, nt*64);
  else if (proj == 1)
    proj_body<1>(smem, kvbf, wk, bk, knw, 1.0f, Kx, mt*128, nt*64);
  else
    proj_body<0>(smem, kvbf, wv, bv, nullptr, 1.0f, V, mt*128, nt*64);
}

// ---------------- O projection: 128x64 tile, 512 blocks (2 blocks/CU) ----------------
__global__ __launch_bounds__(256) void gemm_o(
  const ushort* __restrict__ X, const ushort* __restrict__ wo,
  const float* __restrict__ bo, float* __restrict__ out)
{
  __shared__ char smem[24576];
  ushort* As = (ushort*)smem;
  ushort* Bs = (ushort*)(smem + 16384);
  int bid = (blockIdx.x & 7) * 64 + (blockIdx.x >> 3);   // XCD swizzle (512 = 8 * 64)
  const int mt = bid >> 4, nt = bid & 15;
  const int m0 = mt*128, n0 = nt*64;

  const int tid  = threadIdx.x;
  const int w    = tid >> 6, lid = tid & 63;
  const int lrow = lid & 15, g = lid >> 4;
  const int wm   = (w >> 1) << 6, wn = (w & 1) << 5;   // wave: 64 rows x 32 cols

  f32x4 acc[4][2] = {};

  for (int kt = 0; kt < Dd; kt += 64){
    __syncthreads();
    #pragma unroll
    for (int i = 0; i < 4; ++i){
      int e   = tid + i*256;
      int row = e >> 3;
      int c   = (e & 7) ^ (row & 7);
      gload16(X + (size_t)(m0 + row)*Dd + kt + c*8, &As[e*8]);
    }
    #pragma unroll
    for (int i = 0; i < 2; ++i){
      int e   = tid + i*256;
      int row = e >> 3;
      int c   = (e & 7) ^ (row & 7);
      gload16(wo + (size_t)(n0 + row)*Dd + kt + c*8, &Bs[e*8]);
    }
    __syncthreads();
    #pragma unroll
    for (int kc = 0; kc < 2; ++kc){
      bf16x8 af[4], bfr[2];
      #pragma unroll
      for (int r = 0; r < 4; ++r){
        int row = wm + r*16 + lrow;
        af[r] = *(const bf16x8*)&As[row*64 + (((kc*4 + g) ^ (row & 7)) << 3)];
      }
      #pragma unroll
      for (int c = 0; c < 2; ++c){
        int row = wn + c*16 + lrow;
        bfr[c] = *(const bf16x8*)&Bs[row*64 + (((kc*4 + g) ^ (row & 7)) << 3)];
      }
      #pragma unroll
      for (int r = 0; r < 4; ++r)
        #pragma unroll
        for (int c = 0; c < 2; ++c)
          acc[r][c] = __builtin_amdgcn_mfma_f32_16x16x32_bf16(af[r], bfr[c], acc[r][c], 0, 0, 0);
    }
  }
  const int colbase = n0 + wn;
  float bv[2];
  #pragma unroll
  for (int c = 0; c < 2; ++c) bv[c] = bo[colbase + c*16 + lrow];
  #pragma unroll
  for (int r = 0; r < 4; ++r){
    #pragma unroll
    for (int b = 0; b < 4; ++b){
      int row = m0 + wm + r*16 + g*4 + b;
      #pragma unroll
      for (int c = 0; c < 2; ++c){
        int col = colbase + c*16 + lrow;
        out[(size_t)row*Dd + col] = acc[r][c][b] + bv[c];
      }
    }
  }
}

// ---------------- flash attention: 32x32 MFMA, static-max softmax ----------------
// (round-13 verified kernel, verbatim — 54 us, absmax 1.46e-3)
__global__ __launch_bounds__(256, 2) void attn_k(
  const ushort* __restrict__ Qb, const ushort* __restrict__ Kb,
  const ushort* __restrict__ Vb, ushort* __restrict__ Ob)
{
  __shared__ char L[65536];   // half h at h*32768: K dbuf 2x8KB, V dbuf 2x8KB

  const int tid  = threadIdx.x;
  const int w    = tid >> 6, lid = tid & 63;
  const int half = w >> 1,  qw = w & 1;
  const int c31  = lid & 31, hi = lid >> 5;
  const int ti   = tid & 127;          // index within half (2 waves)

  int bid = blockIdx.x;
  int wg  = (bid & 7) * 64 + (bid >> 3);   // 512 blocks -> 8 XCD contiguous chunks
  int bh  = wg >> 4, qt = wg & 15;
  int bb  = bh >> 4, hh = bh & 15;
  const size_t base = (size_t)bb * Tt * Dd + (size_t)hh * HDd;

  // Q fragments (B-operand): qf[sub][kc]; lane holds Q[q=qt*128+qw*64+sub*32+c31][kc*16+hi*8 ..]
  bf16x8 qf[2][4];
  #pragma unroll
  for (int sub = 0; sub < 2; ++sub)
    #pragma unroll
    for (int kc = 0; kc < 4; ++kc)
      qf[sub][kc] = *(const bf16x8*)&Qb[base + (size_t)(qt*128 + qw*64 + sub*32 + c31)*Dd + kc*16 + hi*8];

  char* Kl = L + half*32768;           // K dbuf
  char* Vl = Kl + 16384;               // V dbuf

  // hoisted K-frag offsets [kh][kc]: row = kh*32+c31, chunk (2kc+hi)^(row&7)
  int kfo[2][4];
  #pragma unroll
  for (int kh = 0; kh < 2; ++kh)
    #pragma unroll
    for (int kc = 0; kc < 4; ++kc)
      kfo[kh][kc] = (kh*32 + c31)*128 + (((2*kc + hi) ^ (c31 & 7)) << 4);

  // hoisted V^T-frag offsets [dh][kc']: row = d = dh*32+c31, chunk (2kc'+hi)^F(d)
  int vfo[2][4];
  #pragma unroll
  for (int dh = 0; dh < 2; ++dh){
    int d = dh*32 + c31, F = ((d >> 3) ^ d) & 7;
    #pragma unroll
    for (int kcp = 0; kcp < 4; ++kcp)
      vfo[dh][kcp] = d*128 + (((2*kcp + hi) ^ F) << 4);
  }

  // V^T scatter offsets: thread owns keys key0..+3, d d0..+7
  const int d0 = (ti & 7) * 8, key0 = (ti >> 3) * 4;
  int vso[8];
  {
    int m  = key0 >> 2;
    int c  = ((m >> 2) << 1) | (m & 1);
    int hb = ((m >> 1) & 1) * 8;
    #pragma unroll
    for (int dd = 0; dd < 8; ++dd){
      int d = d0 + dd, F = ((d >> 3) ^ d) & 7;
      vso[dd] = d*128 + ((c ^ F) << 4) + hb;
    }
  }

  // staging sources (running) + K LDS dests
  const ushort* ksg[4]; char* kdst[4];
  #pragma unroll
  for (int i = 0; i < 4; ++i){
    int e = ti + i*128;
    int row = e >> 3, cc = (e & 7) ^ (row & 7);
    ksg[i]  = Kb + base + (size_t)(half*1024 + row) * Dd + cc*8;
    kdst[i] = Kl + e*16;
  }
  const ushort* vsg = Vb + base + (size_t)(half*1024 + key0) * Dd + d0;
  const size_t kstep = (size_t)64 * Dd;

  // prologue: tile 0 -> buffer 0
  #pragma unroll
  for (int i = 0; i < 4; ++i) gload16(ksg[i], kdst[i]);
  u32x4 vv0 = *(const u32x4*)(vsg);
  u32x4 vv1 = *(const u32x4*)(vsg + Dd);
  u32x4 vv2 = *(const u32x4*)(vsg + 2*Dd);
  u32x4 vv3 = *(const u32x4*)(vsg + 3*Dd);
  #pragma unroll
  for (int i = 0; i < 4; ++i) ksg[i] += kstep;
  vsg += kstep;

  f32x16 o[2][2] = {};          // o[sub][dh]: O^T[d = dh*32+(reg&3)+8(reg>>2)+4hi][q = c31]
  f32x16 lacc[2] = {};          // row-sum accumulators (all regs equal per lane)
  const __bf16 one1 = (__bf16)1.0f;
  const bf16x8 ones = {one1, one1, one1, one1, one1, one1, one1, one1};

  // V^T scatter: 16 v_perm + 8 ds_write_b64
  auto vscatter = [&](int bufoff){
    #pragma unroll
    for (int dd = 0; dd < 8; ++dd){
      unsigned sel = (dd & 1) ? 0x07060302u : 0x05040100u;
      unsigned lo  = __builtin_amdgcn_perm(vv1[dd >> 1], vv0[dd >> 1], sel);
      unsigned hi2 = __builtin_amdgcn_perm(vv3[dd >> 1], vv2[dd >> 1], sel);
      *(uint2*)(Vl + vso[dd] + bufoff) = make_uint2(lo, hi2);
    }
  };

  // static-max softmax: P = exp2(s) in place (|s|<=11.54 guaranteed), then pack.
  auto dosm = [&](f32x16* s, bf16x8* pao){
    #pragma unroll
    for (int kh = 0; kh < 2; ++kh)
      #pragma unroll
      for (int i = 0; i < 16; ++i)
        s[kh][i] = __builtin_amdgcn_exp2f(s[kh][i]);
    // pack B-frags: pao[kc'=2kh+c] slot j = p-reg 8c+j of s[kh]  (key map matches V^T chunks)
    #pragma unroll
    for (int kh = 0; kh < 2; ++kh)
      #pragma unroll
      for (int c = 0; c < 2; ++c){
        unsigned u0, u1, u2, u3;
        asm("v_cvt_pk_bf16_f32 %0, %1, %2" : "=v"(u0) : "v"(s[kh][8*c+0]), "v"(s[kh][8*c+1]));
        asm("v_cvt_pk_bf16_f32 %0, %1, %2" : "=v"(u1) : "v"(s[kh][8*c+2]), "v"(s[kh][8*c+3]));
        asm("v_cvt_pk_bf16_f32 %0, %1, %2" : "=v"(u2) : "v"(s[kh][8*c+4]), "v"(s[kh][8*c+5]));
        asm("v_cvt_pk_bf16_f32 %0, %1, %2" : "=v"(u3) : "v"(s[kh][8*c+6]), "v"(s[kh][8*c+7]));
        u32x4 uu = {u0, u1, u2, u3};
        pao[kh*2 + c] = __builtin_bit_cast(bf16x8, uu);
      }
  };

#define ATTN_TILE(BUF, PREFETCH)                                                     \
  {                                                                                  \
    vscatter((BUF)*8192);                                                            \
    __syncthreads();                                                                 \
    if (PREFETCH){                                                                   \
      _Pragma("unroll")                                                              \
      for (int i = 0; i < 4; ++i){                                                   \
        gload16(ksg[i], kdst[i] + ((BUF)^1)*8192);                                   \
        ksg[i] += kstep;                                                             \
      }                                                                              \
      vv0 = *(const u32x4*)(vsg);                                                    \
      vv1 = *(const u32x4*)(vsg + Dd);                                               \
      vv2 = *(const u32x4*)(vsg + 2*Dd);                                             \
      vv3 = *(const u32x4*)(vsg + 3*Dd);                                             \
      vsg += kstep;                                                                  \
    }                                                                                \
    f32x16 s0[2] = {}, s1[2] = {};                                                   \
    __builtin_amdgcn_s_setprio(1);                                                   \
    _Pragma("unroll")                                                                \
    for (int kh = 0; kh < 2; ++kh)                                                   \
      _Pragma("unroll")                                                              \
      for (int kc = 0; kc < 4; ++kc){                                                \
        bf16x8 kf = *(const bf16x8*)(Kl + kfo[kh][kc] + (BUF)*8192);                 \
        s0[kh] = __builtin_amdgcn_mfma_f32_32x32x16_bf16(kf, qf[0][kc], s0[kh], 0,0,0); \
        s1[kh] = __builtin_amdgcn_mfma_f32_32x32x16_bf16(kf, qf[1][kc], s1[kh], 0,0,0); \
      }                                                                              \
    __builtin_amdgcn_s_setprio(0);                                                   \
    bf16x8 pa0[4], pa1[4];                                                           \
    dosm(s0, pa0);                                                                   \
    dosm(s1, pa1);                                                                   \
    __builtin_amdgcn_s_setprio(1);                                                   \
    _Pragma("unroll")                                                                \
    for (int dh = 0; dh < 2; ++dh)                                                   \
      _Pragma("unroll")                                                              \
      for (int kcp = 0; kcp < 4; ++kcp){                                             \
        bf16x8 vf = *(const bf16x8*)(Vl + vfo[dh][kcp] + (BUF)*8192);                \
        o[0][dh] = __builtin_amdgcn_mfma_f32_32x32x16_bf16(vf, pa0[kcp], o[0][dh], 0,0,0); \
        o[1][dh] = __builtin_amdgcn_mfma_f32_32x32x16_bf16(vf, pa1[kcp], o[1][dh], 0,0,0); \
      }                                                                              \
    _Pragma("unroll")                                                                \
    for (int kcp = 0; kcp < 4; ++kcp){                                               \
      lacc[0] = __builtin_amdgcn_mfma_f32_32x32x16_bf16(ones, pa0[kcp], lacc[0], 0,0,0); \
      lacc[1] = __builtin_amdgcn_mfma_f32_32x32x16_bf16(ones, pa1[kcp], lacc[1], 0,0,0); \
    }                                                                                \
    __builtin_amdgcn_s_setprio(0);                                                   \
  }

  for (int kt2 = 0; kt2 < 8; ++kt2){
    ATTN_TILE(0, true);
    ATTN_TILE(1, (kt2 != 7));
  }
#undef ATTN_TILE

  // ---- merge halves through LDS: layout pub[i][ti] f32x4, i=0..16 (17*128*16B = 34 KB)
  __syncthreads();
  if (half == 1){
    #pragma unroll
    for (int sub = 0; sub < 2; ++sub)
      #pragma unroll
      for (int dh = 0; dh < 2; ++dh)
        #pragma unroll
        for (int G = 0; G < 4; ++G){
          f32x4 v = { o[sub][dh][4*G+0], o[sub][dh][4*G+1], o[sub][dh][4*G+2], o[sub][dh][4*G+3] };
          *(f32x4*)(L + (((sub*8 + dh*4 + G)*128) + ti)*16) = v;
        }
    f32x4 ml = {lacc[0][0], lacc[1][0], 0.f, 0.f};
    *(f32x4*)(L + ((16*128) + ti)*16) = ml;
  }
  __syncthreads();
  if (half == 0){
    f32x4 ml = *(const f32x4*)(L + ((16*128) + ti)*16);
    #pragma unroll
    for (int sub = 0; sub < 2; ++sub){
      float inv = 1.0f / (lacc[sub][0] + ml[sub]);
      int qrow = qt*128 + qw*64 + sub*32 + c31;
      #pragma unroll
      for (int dh = 0; dh < 2; ++dh)
        #pragma unroll
        for (int G = 0; G < 4; ++G){
          f32x4 op = *(const f32x4*)(L + (((sub*8 + dh*4 + G)*128) + ti)*16);
          float oc0 = (o[sub][dh][4*G+0] + op[0]) * inv;
          float oc1 = (o[sub][dh][4*G+1] + op[1]) * inv;
          float oc2 = (o[sub][dh][4*G+2] + op[2]) * inv;
          float oc3 = (o[sub][dh][4*G+3] + op[3]) * inv;
          uint2 u;
          u.x = (unsigned)f2bf(oc0) | ((unsigned)f2bf(oc1) << 16);
          u.y = (unsigned)f2bf(oc2) | ((unsigned)f2bf(oc3) << 16);
          *(uint2*)&Ob[base + (size_t)qrow*Dd + dh*32 + 8*G + hi*4] = u;
        }
    }
  }
}

extern "C" void kernel_launch(void* const* d_in, const int* in_sizes, int n_in,
                              void* d_out, int out_size, void* d_ws, size_t ws_size,
                              hipStream_t stream)
{
  const float* query = (const float*)d_in[0];
  const float* keyv  = (const float*)d_in[1];
  const float* Wq    = (const float*)d_in[2];
  const float* bq    = (const float*)d_in[3];
  const float* Wk    = (const float*)d_in[4];
  const float* bk    = (const float*)d_in[5];
  const float* Wv    = (const float*)d_in[6];
  const float* bv    = (const float*)d_in[7];
  const float* Wo    = (const float*)d_in[8];
  const float* bo    = (const float*)d_in[9];
  const float* qnw   = (const float*)d_in[10];
  const float* knw   = (const float*)d_in[11];
  float* out = (float*)d_out;

  char* p = (char*)d_ws;
  ushort* qbf  = (ushort*)p; p += (size_t)Mm*Dd*2;
  ushort* kvbf = (ushort*)p; p += (size_t)Mm*Dd*2;
  ushort* wqb  = (ushort*)p; p += (size_t)Dd*Dd*2;
  ushort* wkb  = (ushort*)p; p += (size_t)Dd*Dd*2;
  ushort* wvb  = (ushort*)p; p += (size_t)Dd*Dd*2;
  ushort* wob  = (ushort*)p; p += (size_t)Dd*Dd*2;
  ushort* Qb   = (ushort*)p; p += (size_t)Mm*Dd*2;
  ushort* Kbf  = (ushort*)p; p += (size_t)Mm*Dd*2;
  ushort* Vbf  = (ushort*)p; p += (size_t)Mm*Dd*2;
  ushort* Ab   = (ushort*)p; p += (size_t)Mm*Dd*2;

  cvt_all<<<dim3(12288), dim3(256), 0, stream>>>(query, keyv, Wq, Wk, Wv, Wo,
                                                 qbf, kvbf, wqb, wkb, wvb, wob);

  gemm_qkv<<<dim3(1536), dim3(256), 0, stream>>>(qbf, kvbf, wqb, wkb, wvb,
                                                 bq, bk, bv, qnw, knw, Qb, Kbf, Vbf);

  attn_k<<<dim3(512), dim3(256), 0, stream>>>(Qb, Kbf, Vbf, Ab);

  gemm_o<<<dim3(512), dim3(256), 0, stream>>>(Ab, wob, bo, out);
}